// Round 4
// baseline (3692.370 us; speedup 1.0000x reference)
//
#include <hip/hip_runtime.h>
#include <math.h>

#define N_NODES 16384
#define N_EDGES 262144
#define TOW 5
#define FI 75            // F_IN
#define FO 15            // F_OUT
#define DE 50
#define NL 4
#define NG 256
#define HWP 752          // padded node stride: [hWi 0..374][pad][hWj 376..750][pad]
#define NPN 4            // nodes per k_fuse block

static __device__ __attribute__((aligned(16))) float g_hA[N_NODES*FI];
static __device__ __attribute__((aligned(16))) float g_hB[N_NODES*FI];
static __device__ __attribute__((aligned(16))) float g_hW[N_NODES*HWP];
static __device__ __attribute__((aligned(16))) float g_ec[NL*4*376];
static __device__ __attribute__((aligned(16))) float g_qwT[NL*TOW*3*FO*300];  // 270000
static __device__ __attribute__((aligned(16))) float g_lwT[NL*75*76];         // 22800
static __device__ __attribute__((aligned(16))) float g_pwT[NL*750*76];        // 228000
static __device__ int   g_deg[N_NODES];
static __device__ int   g_rowstart[N_NODES+1];
static __device__ int   g_cursor[N_NODES];
static __device__ int   g_edge[N_EDGES];
static __device__ float g_mu[FI];
static __device__ float g_rsig[FI];
static __device__ float g_pool[NG*FI];

__global__ void k_embed(const int* __restrict__ x, const float* __restrict__ node_emb) {
    int i = blockIdx.x * blockDim.x + threadIdx.x;
    if (i < N_NODES*FI) {
        int n = i / FI, f = i % FI;
        g_hA[i] = node_emb[x[n]*FI + f];
    }
}

__global__ void k_zerodeg() {
    int i = blockIdx.x * blockDim.x + threadIdx.x;
    if (i < N_NODES) g_deg[i] = 0;
}

__global__ void k_hist(const int* __restrict__ dst) {
    int e = blockIdx.x * blockDim.x + threadIdx.x;
    if (e < N_EDGES) atomicAdd(&g_deg[dst[e]], 1);
}

__global__ void k_scan() {
    __shared__ int part[1024];
    int t = threadIdx.x;
    int base = t * 16;
    int loc[16];
    int s = 0;
    #pragma unroll
    for (int i = 0; i < 16; i++) { loc[i] = s; s += g_deg[base + i]; }
    part[t] = s;
    __syncthreads();
    for (int off = 1; off < 1024; off <<= 1) {
        int v = 0;
        if (t >= off) v = part[t - off];
        __syncthreads();
        if (t >= off) part[t] += v;
        __syncthreads();
    }
    int excl = (t == 0) ? 0 : part[t - 1];
    #pragma unroll
    for (int i = 0; i < 16; i++) {
        g_rowstart[base + i] = excl + loc[i];
        g_cursor[base + i]   = excl + loc[i];
    }
    if (t == 1023) g_rowstart[N_NODES] = part[1023];
}

__global__ void k_scatter(const int* __restrict__ src, const int* __restrict__ dst,
                          const int* __restrict__ attr) {
    int e = blockIdx.x * blockDim.x + threadIdx.x;
    if (e < N_EDGES) {
        int d = dst[e];
        int pos = atomicAdd(&g_cursor[d], 1);
        g_edge[pos] = src[e] | (attr[e] << 16);
    }
}

// one-time weight transposes:
//  qwT[l][(tw*3+s)*15+g][300]   (270000)
//  lwT[l][g2][76] pad           (22800)
//  pwT[l][half*375+tw*75+g][76] (228000)
__global__ void k_wt(const float* __restrict__ post_w, const float* __restrict__ lin_w,
                     const float* __restrict__ pre_w) {
    int i = blockIdx.x * blockDim.x + threadIdx.x;
    const int TOT_Q = NL*TOW*900*FO;           // 270000
    const int TOT_L = NL*75*76;                // 22800
    const int TOT_P = NL*750*76;               // 228000
    if (i < TOT_Q) {
        int g = i % FO;
        int r = i / FO;
        int f = r % 900;
        int lt = r / 900;
        int s = f / 300, fr = f % 300;
        g_qwT[((lt*3 + s)*FO + g)*300 + fr] = post_w[i];
        return;
    }
    int j = i - TOT_Q;
    if (j < TOT_L) {
        int f  = j % 76;
        int r  = j / 76;
        int g2 = r % 75;
        int l  = r / 75;
        g_lwT[j] = (f < 75) ? lin_w[(l*75 + f)*75 + g2] : 0.f;
        return;
    }
    int k = j - TOT_L;
    if (k < TOT_P) {
        int f = k % 76;
        int row = k / 76;
        int o = row % 750;
        int l = row / 750;
        int half = o / 375;
        int r = o % 375;
        int tw = r / 75, g = r % 75;
        g_pwT[k] = (f < 75) ? pre_w[((l*TOW + tw)*225 + half*75 + f)*75 + g] : 0.f;
    }
}

// all-layer edge contribution tables: g_ec[l][a][376]
__global__ void k_ec(const float* __restrict__ edge_emb, const float* __restrict__ edge_enc_w,
                     const float* __restrict__ edge_enc_b, const float* __restrict__ pre_w,
                     const float* __restrict__ pre_b) {
    int l = blockIdx.x;
    const float* eew = edge_enc_w + l*DE*FI;
    const float* eeb = edge_enc_b + l*FI;
    const float* pw  = pre_w + l*TOW*3*FI*FI;
    const float* pb  = pre_b + l*TOW*FI;
    __shared__ float e_enc[4*FI];
    int t = threadIdx.x;
    if (t < 4*FI) {
        int a = t / FI, f = t % FI;
        float s = eeb[f];
        for (int d = 0; d < DE; d++) s += edge_emb[a*DE + d] * eew[d*FI + f];
        e_enc[t] = s;
    }
    __syncthreads();
    for (int o = t; o < 4*376; o += blockDim.x) {
        int a = o / 376;
        int r = o % 376;
        float s = 0.f;
        if (r < TOW*FI) {
            int tw = r / FI, g = r % FI;
            s = pb[tw*FI + g];
            const float* W = pw + (tw*(3*FI) + 2*FI)*FI + g;
            for (int f = 0; f < FI; f++) s += e_enc[a*FI + f] * W[f*FI];
        }
        g_ec[l*1504 + o] = s;
    }
}

// node transform (transposed weights, float4) with fused BN+ReLU of prev layer
#define NPB 8
__global__ void k_hw(int l, const float* __restrict__ gamma,
                     const float* __restrict__ beta, int first) {
    __shared__ __align__(16) float hsh[NPB][76];
    int n0 = blockIdx.x * NPB;
    int tid = threadIdx.x;
    for (int i = tid; i < NPB*76; i += blockDim.x) {
        int nn = i / 76, f = i % 76;
        float v = 0.f;
        if (f < 75) {
            int idx = (n0 + nn)*FI + f;
            if (first) {
                v = g_hA[idx];
            } else {
                v = (g_hB[idx] - g_mu[f]) * g_rsig[f] * gamma[f] + beta[f];
                v = v > 0.f ? v : 0.f;
            }
        }
        hsh[nn][f] = v;
    }
    __syncthreads();
    const float* pwT = g_pwT + l*750*76;
    for (int o = tid; o < 750; o += blockDim.x) {
        const float4* w4 = (const float4*)&pwT[o*76];
        float acc[NPB];
        #pragma unroll
        for (int nn = 0; nn < NPB; nn++) acc[nn] = 0.f;
        for (int fq = 0; fq < 19; fq++) {
            float4 w = w4[fq];
            #pragma unroll
            for (int nn = 0; nn < NPB; nn++) {
                float4 h = *(const float4*)&hsh[nn][4*fq];
                acc[nn] += h.x*w.x + h.y*w.y + h.z*w.z + h.w*w.w;
            }
        }
        int half = o / 375, r = o % 375;
        #pragma unroll
        for (int nn = 0; nn < NPB; nn++)
            g_hW[(n0+nn)*HWP + half*376 + r] = acc[nn];
    }
}

// fused: edge aggregation (shfl-reduce) + post GEMM (qwT streamed) + lin, NPN nodes/block
__global__ __launch_bounds__(384) void
k_fuse(int l, const float* __restrict__ qb, const float* __restrict__ lb) {
    __shared__ __align__(16) float agg[NPN*1500];   // 24 KB  [nn][tw*300+kind*75+f]
    __shared__ __align__(16) float4 part4[375];     // 6 KB
    __shared__ __align__(16) float post[NPN][80];   // 1.28 KB
    __shared__ float s_amp[NPN], s_iamp[NPN];

    int tid = threadIdx.x;
    int n0 = blockIdx.x * NPN;
    int el = tid & 3;
    int q  = tid >> 2;
    bool act = q < 94;
    const float* ec = g_ec + l*1504;

    for (int nn = 0; nn < NPN; nn++) {
        int n  = n0 + nn;
        int e0 = g_rowstart[n], e1 = g_rowstart[n+1];
        int cnt = e1 - e0;

        float s0=0.f,s1=0.f,s2=0.f,s3=0.f;
        float t0=0.f,t1=0.f,t2=0.f,t3=0.f;
        float mn0=1e30f,mn1=1e30f,mn2=1e30f,mn3=1e30f;
        float mx0=-1e30f,mx1=-1e30f,mx2=-1e30f,mx3=-1e30f;
        float h0=0.f,h1=0.f,h2=0.f,h3=0.f;
        if (act) {
            float4 hv = *(const float4*)&g_hW[n*HWP + 4*q];
            h0=hv.x; h1=hv.y; h2=hv.z; h3=hv.w;
        }
        for (int e = e0 + el; e < e1; e += 4) {
            int pk = g_edge[e];
            int sn = pk & 0xFFFF;
            int a  = pk >> 16;
            if (act) {
                float4 hj = *(const float4*)&g_hW[sn*HWP + 376 + 4*q];
                float4 ev = *(const float4*)&ec[a*376 + 4*q];
                float m0 = h0 + hj.x + ev.x;
                float m1 = h1 + hj.y + ev.y;
                float m2 = h2 + hj.z + ev.z;
                float m3 = h3 + hj.w + ev.w;
                s0 += m0; s1 += m1; s2 += m2; s3 += m3;
                t0 += m0*m0; t1 += m1*m1; t2 += m2*m2; t3 += m3*m3;
                mn0 = fminf(mn0,m0); mn1 = fminf(mn1,m1);
                mn2 = fminf(mn2,m2); mn3 = fminf(mn3,m3);
                mx0 = fmaxf(mx0,m0); mx1 = fmaxf(mx1,m1);
                mx2 = fmaxf(mx2,m2); mx3 = fmaxf(mx3,m3);
            }
        }
        #define RSUM(v) v += __shfl_xor(v,1); v += __shfl_xor(v,2);
        #define RMIN(v) v = fminf(v,__shfl_xor(v,1)); v = fminf(v,__shfl_xor(v,2));
        #define RMAX(v) v = fmaxf(v,__shfl_xor(v,1)); v = fmaxf(v,__shfl_xor(v,2));
        RSUM(s0) RSUM(s1) RSUM(s2) RSUM(s3)
        RSUM(t0) RSUM(t1) RSUM(t2) RSUM(t3)
        RMIN(mn0) RMIN(mn1) RMIN(mn2) RMIN(mn3)
        RMAX(mx0) RMAX(mx1) RMAX(mx2) RMAX(mx3)

        if (act && el == 0) {
            float inv = 1.0f / ((cnt > 0) ? (float)cnt : 1.0f);
            float sv[4]  = {s0,s1,s2,s3};
            float tv[4]  = {t0,t1,t2,t3};
            float mnv[4] = {mn0,mn1,mn2,mn3};
            float mxv[4] = {mx0,mx1,mx2,mx3};
            #pragma unroll
            for (int j = 0; j < 4; j++) {
                int c = 4*q + j;
                if (c < TOW*FI) {
                    int tw = c / FI, f = c - tw*FI;
                    float mean  = sv[j]*inv;
                    float mean2 = tv[j]*inv;
                    float var = mean2 - mean*mean;
                    if (var < 0.f) var = 0.f;
                    int b = nn*1500 + tw*300 + f;
                    agg[b      ] = mean;
                    agg[b +  75] = (cnt > 0) ? mnv[j] : 0.f;
                    agg[b + 150] = (cnt > 0) ? mxv[j] : 0.f;
                    agg[b + 225] = sqrtf(var + 1e-5f);
                }
            }
        }
        if (tid == 0) {
            float deg = (cnt > 0) ? (float)cnt : 1.0f;
            float amp = logf(deg + 1.0f) * (1.0f/2.8332133440562162f);
            s_amp[nn] = amp; s_iamp[nn] = 1.0f/amp;
        }
    }
    __syncthreads();

    float amp[NPN], iamp[NPN];
    #pragma unroll
    for (int nn = 0; nn < NPN; nn++) { amp[nn] = s_amp[nn]; iamp[nn] = s_iamp[nn]; }

    // post partials: thread (o = tw*15+g, p), f-slice [p*60, p*60+60)
    const float* qwT = g_qwT + l*67500;
    if (tid < 375) {
        int o = tid % 75;
        int p = tid / 75;
        int tw = o / FO, g = o % FO;
        float acc[3][NPN];
        #pragma unroll
        for (int s = 0; s < 3; s++)
            #pragma unroll
            for (int nn = 0; nn < NPN; nn++) acc[s][nn] = 0.f;
        #pragma unroll
        for (int s = 0; s < 3; s++) {
            const float4* w4 = (const float4*)&qwT[((tw*3+s)*FO + g)*300 + p*60];
            for (int fq = 0; fq < 15; fq++) {
                float4 w = w4[fq];
                #pragma unroll
                for (int nn = 0; nn < NPN; nn++) {
                    float4 a = *(const float4*)&agg[nn*1500 + tw*300 + p*60 + 4*fq];
                    acc[s][nn] += a.x*w.x + a.y*w.y + a.z*w.z + a.w*w.w;
                }
            }
        }
        float4 r;
        r.x = acc[0][0] + amp[0]*acc[1][0] + iamp[0]*acc[2][0];
        r.y = acc[0][1] + amp[1]*acc[1][1] + iamp[1]*acc[2][1];
        r.z = acc[0][2] + amp[2]*acc[1][2] + iamp[2]*acc[2][2];
        r.w = acc[0][3] + amp[3]*acc[1][3] + iamp[3]*acc[2][3];
        part4[p*75 + o] = r;
    }
    __syncthreads();
    if (tid < 75) {
        float4 a = part4[tid];
        #pragma unroll
        for (int p = 1; p < 5; p++) {
            float4 b = part4[p*75 + tid];
            a.x += b.x; a.y += b.y; a.z += b.z; a.w += b.w;
        }
        float qbv = qb[tid];
        post[0][tid] = qbv + a.x;
        post[1][tid] = qbv + a.y;
        post[2][tid] = qbv + a.z;
        post[3][tid] = qbv + a.w;
    }
    __syncthreads();
    // lin partials: thread (o=g2, p), f-slice [p*15, p*15+15)
    const float* lwT = g_lwT + l*75*76;
    if (tid < 375) {
        int o = tid % 75;
        int p = tid / 75;
        const float* w = &lwT[o*76 + p*15];
        float sp[NPN] = {0.f,0.f,0.f,0.f};
        for (int f = 0; f < 15; f++) {
            float wv = w[f];
            int fi = p*15 + f;
            #pragma unroll
            for (int nn = 0; nn < NPN; nn++) sp[nn] += post[nn][fi] * wv;
        }
        part4[p*75 + o] = make_float4(sp[0],sp[1],sp[2],sp[3]);
    }
    __syncthreads();
    if (tid < 75) {
        float4 a = part4[tid];
        #pragma unroll
        for (int p = 1; p < 5; p++) {
            float4 b = part4[p*75 + tid];
            a.x += b.x; a.y += b.y; a.z += b.z; a.w += b.w;
        }
        float lbv = lb[tid];
        g_hB[(n0+0)*FI + tid] = lbv + a.x;
        g_hB[(n0+1)*FI + tid] = lbv + a.y;
        g_hB[(n0+2)*FI + tid] = lbv + a.z;
        g_hB[(n0+3)*FI + tid] = lbv + a.w;
    }
}

__global__ void k_bnstat() {
    int c = blockIdx.x;
    int t = threadIdx.x;
    double s = 0.0, s2 = 0.0;
    for (int n = t; n < N_NODES; n += 256) {
        float v = g_hB[n*FI + c];
        s += v; s2 += (double)v * v;
    }
    __shared__ double ps[256], ps2[256];
    ps[t] = s; ps2[t] = s2;
    __syncthreads();
    for (int off = 128; off > 0; off >>= 1) {
        if (t < off) { ps[t] += ps[t+off]; ps2[t] += ps2[t+off]; }
        __syncthreads();
    }
    if (t == 0) {
        double mu = ps[0] / N_NODES;
        double var = ps2[0] / N_NODES - mu*mu;
        if (var < 0.0) var = 0.0;
        g_mu[c]   = (float)mu;
        g_rsig[c] = (float)(1.0 / sqrt(var + 1e-5));
    }
}

__global__ void k_poolzero() {
    int i = blockIdx.x * blockDim.x + threadIdx.x;
    if (i < NG*FI) g_pool[i] = 0.f;
}

__global__ void k_pool(const int* __restrict__ batch, const float* __restrict__ gamma,
                       const float* __restrict__ beta) {
    int i = blockIdx.x * blockDim.x + threadIdx.x;
    if (i < N_NODES*FI) {
        int n = i / FI, c = i % FI;
        float v = (g_hB[i] - g_mu[c]) * g_rsig[c] * gamma[c] + beta[c];
        v = v > 0.f ? v : 0.f;
        atomicAdd(&g_pool[batch[n]*FI + c], v);
    }
}

__global__ void k_mlp(const float* __restrict__ w1, const float* __restrict__ b1,
                      const float* __restrict__ w2, const float* __restrict__ b2,
                      const float* __restrict__ w3, const float* __restrict__ b3,
                      float* __restrict__ out) {
    __shared__ float gin[FI], h1[50], h2[25];
    int gi = blockIdx.x;
    int t = threadIdx.x;
    if (t < FI) gin[t] = g_pool[gi*FI + t];
    __syncthreads();
    if (t < 50) {
        float s = b1[t];
        for (int f = 0; f < FI; f++) s += gin[f] * w1[f*50 + t];
        h1[t] = s > 0.f ? s : 0.f;
    }
    __syncthreads();
    if (t < 25) {
        float s = b2[t];
        for (int f = 0; f < 50; f++) s += h1[f] * w2[f*25 + t];
        h2[t] = s > 0.f ? s : 0.f;
    }
    __syncthreads();
    if (t == 0) {
        float s = b3[0];
        for (int f = 0; f < 25; f++) s += h2[f] * w3[f];
        out[gi] = s;
    }
}

extern "C" void kernel_launch(void* const* d_in, const int* in_sizes, int n_in,
                              void* d_out, int out_size, void* d_ws, size_t ws_size,
                              hipStream_t stream) {
    const int*   x          = (const int*)  d_in[0];
    const int*   edge_index = (const int*)  d_in[1];
    const int*   edge_attr  = (const int*)  d_in[2];
    const int*   batch      = (const int*)  d_in[3];
    const float* node_emb   = (const float*)d_in[4];
    const float* edge_emb   = (const float*)d_in[5];
    const float* edge_enc_w = (const float*)d_in[6];
    const float* edge_enc_b = (const float*)d_in[7];
    const float* pre_w      = (const float*)d_in[8];
    const float* pre_b      = (const float*)d_in[9];
    const float* post_w     = (const float*)d_in[10];
    const float* post_b     = (const float*)d_in[11];
    const float* lin_w      = (const float*)d_in[12];
    const float* lin_b      = (const float*)d_in[13];
    const float* bn_gamma   = (const float*)d_in[14];
    const float* bn_beta    = (const float*)d_in[15];
    const float* mlp_w1     = (const float*)d_in[16];
    const float* mlp_b1     = (const float*)d_in[17];
    const float* mlp_w2     = (const float*)d_in[18];
    const float* mlp_b2     = (const float*)d_in[19];
    const float* mlp_w3     = (const float*)d_in[20];
    const float* mlp_b3     = (const float*)d_in[21];
    float* out = (float*)d_out;

    const int* src = edge_index;
    const int* dst = edge_index + N_EDGES;

    k_embed<<<(N_NODES*FI + 255)/256, 256, 0, stream>>>(x, node_emb);
    k_zerodeg<<<(N_NODES + 255)/256, 256, 0, stream>>>();
    k_hist<<<(N_EDGES + 255)/256, 256, 0, stream>>>(dst);
    k_scan<<<1, 1024, 0, stream>>>();
    k_scatter<<<(N_EDGES + 255)/256, 256, 0, stream>>>(src, dst, edge_attr);
    k_wt<<<(270000 + 22800 + 228000 + 255)/256, 256, 0, stream>>>(post_w, lin_w, pre_w);
    k_ec<<<NL, 512, 0, stream>>>(edge_emb, edge_enc_w, edge_enc_b, pre_w, pre_b);

    for (int l = 0; l < NL; l++) {
        const float* qb  = post_b + l*TOW*FO;
        const float* lb  = lin_b  + l*TOW*FO;
        const float* gamP = bn_gamma + (l > 0 ? (l-1)*FI : 0);
        const float* betP = bn_beta  + (l > 0 ? (l-1)*FI : 0);

        k_hw<<<N_NODES/NPB, 256, 0, stream>>>(l, gamP, betP, l == 0 ? 1 : 0);
        k_fuse<<<N_NODES/NPN, 384, 0, stream>>>(l, qb, lb);
        k_bnstat<<<FI, 256, 0, stream>>>();
    }

    k_poolzero<<<(NG*FI + 255)/256, 256, 0, stream>>>();
    k_pool<<<(N_NODES*FI + 255)/256, 256, 0, stream>>>(batch, bn_gamma + 3*FI, bn_beta + 3*FI);
    k_mlp<<<NG, 128, 0, stream>>>(mlp_w1, mlp_b1, mlp_w2, mlp_b2, mlp_w3, mlp_b3, out);
}

// Round 5
// 2889.314 us; speedup vs baseline: 1.2779x; 1.2779x over previous
//
#include <hip/hip_runtime.h>
#include <math.h>

#define N_NODES 16384
#define N_EDGES 262144
#define TOW 5
#define FI 75            // F_IN
#define FO 15            // F_OUT
#define DE 50
#define NL 4
#define NG 256
#define HWP 752          // padded node stride: [hWi 0..374][pad][hWj 376..750][pad]
#define NPN 4            // nodes per k_fuse block

static __device__ __attribute__((aligned(16))) float g_hA[N_NODES*FI];
static __device__ __attribute__((aligned(16))) float g_hB[N_NODES*FI];
static __device__ __attribute__((aligned(16))) float g_hW[N_NODES*HWP];
static __device__ __attribute__((aligned(16))) float g_ec[NL*4*376];
static __device__ int   g_deg[N_NODES];
static __device__ int   g_rowstart[N_NODES+1];
static __device__ int   g_cursor[N_NODES];
static __device__ int   g_edge[N_EDGES];
static __device__ float g_mu[FI];
static __device__ float g_rsig[FI];
static __device__ float g_pool[NG*FI];

__global__ void k_embed(const int* __restrict__ x, const float* __restrict__ node_emb) {
    int i = blockIdx.x * blockDim.x + threadIdx.x;
    if (i < N_NODES*FI) {
        int n = i / FI, f = i % FI;
        g_hA[i] = node_emb[x[n]*FI + f];
    }
}

__global__ void k_zerodeg() {
    int i = blockIdx.x * blockDim.x + threadIdx.x;
    if (i < N_NODES) g_deg[i] = 0;
}

__global__ void k_hist(const int* __restrict__ dst) {
    int e = blockIdx.x * blockDim.x + threadIdx.x;
    if (e < N_EDGES) atomicAdd(&g_deg[dst[e]], 1);
}

__global__ void k_scan() {
    __shared__ int part[1024];
    int t = threadIdx.x;
    int base = t * 16;
    int loc[16];
    int s = 0;
    #pragma unroll
    for (int i = 0; i < 16; i++) { loc[i] = s; s += g_deg[base + i]; }
    part[t] = s;
    __syncthreads();
    for (int off = 1; off < 1024; off <<= 1) {
        int v = 0;
        if (t >= off) v = part[t - off];
        __syncthreads();
        if (t >= off) part[t] += v;
        __syncthreads();
    }
    int excl = (t == 0) ? 0 : part[t - 1];
    #pragma unroll
    for (int i = 0; i < 16; i++) {
        g_rowstart[base + i] = excl + loc[i];
        g_cursor[base + i]   = excl + loc[i];
    }
    if (t == 1023) g_rowstart[N_NODES] = part[1023];
}

__global__ void k_scatter(const int* __restrict__ src, const int* __restrict__ dst,
                          const int* __restrict__ attr) {
    int e = blockIdx.x * blockDim.x + threadIdx.x;
    if (e < N_EDGES) {
        int d = dst[e];
        int pos = atomicAdd(&g_cursor[d], 1);
        g_edge[pos] = src[e] | (attr[e] << 16);
    }
}

// all-layer edge contribution tables: g_ec[l][a][376]
__global__ void k_ec(const float* __restrict__ edge_emb, const float* __restrict__ edge_enc_w,
                     const float* __restrict__ edge_enc_b, const float* __restrict__ pre_w,
                     const float* __restrict__ pre_b) {
    int l = blockIdx.x;
    const float* eew = edge_enc_w + l*DE*FI;
    const float* eeb = edge_enc_b + l*FI;
    const float* pw  = pre_w + l*TOW*3*FI*FI;
    const float* pb  = pre_b + l*TOW*FI;
    __shared__ float e_enc[4*FI];
    int t = threadIdx.x;
    if (t < 4*FI) {
        int a = t / FI, f = t % FI;
        float s = eeb[f];
        for (int d = 0; d < DE; d++) s += edge_emb[a*DE + d] * eew[d*FI + f];
        e_enc[t] = s;
    }
    __syncthreads();
    for (int o = t; o < 4*376; o += blockDim.x) {
        int a = o / 376;
        int r = o % 376;
        float s = 0.f;
        if (r < TOW*FI) {
            int tw = r / FI, g = r % FI;
            s = pb[tw*FI + g];
            const float* W = pw + (tw*(3*FI) + 2*FI)*FI + g;
            for (int f = 0; f < FI; f++) s += e_enc[a*FI + f] * W[f*FI];
        }
        g_ec[l*1504 + o] = s;
    }
}

// node transform (coalesced scalar weight loads, lane = output dim),
// fused BN+ReLU of previous layer's output
#define NPB 8
__global__ void k_hw(const float* __restrict__ pw, const float* __restrict__ gamma,
                     const float* __restrict__ beta, int first) {
    __shared__ float hsh[NPB*FI];
    int n0 = blockIdx.x * NPB;
    int tid = threadIdx.x;
    for (int i = tid; i < NPB*FI; i += blockDim.x) {
        int idx = (n0 + i/FI)*FI + (i % FI);
        float v;
        if (first) {
            v = g_hA[idx];
        } else {
            int c = i % FI;
            v = (g_hB[idx] - g_mu[c]) * g_rsig[c] * gamma[c] + beta[c];
            v = v > 0.f ? v : 0.f;
        }
        hsh[i] = v;
    }
    __syncthreads();
    for (int o = tid; o < 2*TOW*FI; o += blockDim.x) {
        int half = o / (TOW*FI);
        int r = o % (TOW*FI);
        int tw = r / FI, g = r % FI;
        const float* W = pw + (tw*(3*FI) + half*FI)*FI + g;
        float acc[NPB];
        #pragma unroll
        for (int nn = 0; nn < NPB; nn++) acc[nn] = 0.f;
        for (int f = 0; f < FI; f++) {
            float w = W[f*FI];
            #pragma unroll
            for (int nn = 0; nn < NPB; nn++) acc[nn] += hsh[nn*FI + f] * w;
        }
        #pragma unroll
        for (int nn = 0; nn < NPB; nn++)
            g_hW[(n0+nn)*HWP + half*376 + r] = acc[nn];
    }
}

// fused: edge aggregation (shfl-reduce, no barriers/LDS) + post GEMM + lin
// (original weight layouts, lane = output dim -> coalesced scalar loads)
__global__ __launch_bounds__(384, 6) void
k_fuse(int l, const float* __restrict__ qw, const float* __restrict__ qb,
       const float* __restrict__ lw, const float* __restrict__ lb) {
    __shared__ float agg[NPN*1500];     // 24 KB  [nn][tw*300 + kind*75 + f]
    __shared__ float post[NPN*76];
    __shared__ float s_amp[NPN], s_iamp[NPN];

    int tid = threadIdx.x;
    int n0 = blockIdx.x * NPN;
    int el = tid & 3;
    int q  = tid >> 2;
    bool act = q < 94;
    const float* ec = g_ec + l*1504;

    for (int nn = 0; nn < NPN; nn++) {
        int n  = n0 + nn;
        int e0 = g_rowstart[n], e1 = g_rowstart[n+1];
        int cnt = e1 - e0;

        float s0=0.f,s1=0.f,s2=0.f,s3=0.f;
        float t0=0.f,t1=0.f,t2=0.f,t3=0.f;
        float mn0=1e30f,mn1=1e30f,mn2=1e30f,mn3=1e30f;
        float mx0=-1e30f,mx1=-1e30f,mx2=-1e30f,mx3=-1e30f;
        float h0=0.f,h1=0.f,h2=0.f,h3=0.f;
        if (act) {
            float4 hv = *(const float4*)&g_hW[n*HWP + 4*q];
            h0=hv.x; h1=hv.y; h2=hv.z; h3=hv.w;
        }
        for (int e = e0 + el; e < e1; e += 4) {
            int pk = g_edge[e];
            int sn = pk & 0xFFFF;
            int a  = pk >> 16;
            if (act) {
                float4 hj = *(const float4*)&g_hW[sn*HWP + 376 + 4*q];
                float4 ev = *(const float4*)&ec[a*376 + 4*q];
                float m0 = h0 + hj.x + ev.x;
                float m1 = h1 + hj.y + ev.y;
                float m2 = h2 + hj.z + ev.z;
                float m3 = h3 + hj.w + ev.w;
                s0 += m0; s1 += m1; s2 += m2; s3 += m3;
                t0 += m0*m0; t1 += m1*m1; t2 += m2*m2; t3 += m3*m3;
                mn0 = fminf(mn0,m0); mn1 = fminf(mn1,m1);
                mn2 = fminf(mn2,m2); mn3 = fminf(mn3,m3);
                mx0 = fmaxf(mx0,m0); mx1 = fmaxf(mx1,m1);
                mx2 = fmaxf(mx2,m2); mx3 = fmaxf(mx3,m3);
            }
        }
        #define RSUM(v) v += __shfl_xor(v,1); v += __shfl_xor(v,2);
        #define RMIN(v) v = fminf(v,__shfl_xor(v,1)); v = fminf(v,__shfl_xor(v,2));
        #define RMAX(v) v = fmaxf(v,__shfl_xor(v,1)); v = fmaxf(v,__shfl_xor(v,2));
        RSUM(s0) RSUM(s1) RSUM(s2) RSUM(s3)
        RSUM(t0) RSUM(t1) RSUM(t2) RSUM(t3)
        RMIN(mn0) RMIN(mn1) RMIN(mn2) RMIN(mn3)
        RMAX(mx0) RMAX(mx1) RMAX(mx2) RMAX(mx3)

        if (act && el == 0) {
            float inv = 1.0f / ((cnt > 0) ? (float)cnt : 1.0f);
            float sv[4]  = {s0,s1,s2,s3};
            float tv[4]  = {t0,t1,t2,t3};
            float mnv[4] = {mn0,mn1,mn2,mn3};
            float mxv[4] = {mx0,mx1,mx2,mx3};
            #pragma unroll
            for (int j = 0; j < 4; j++) {
                int c = 4*q + j;
                if (c < TOW*FI) {
                    int tw = c / FI, f = c - tw*FI;
                    float mean  = sv[j]*inv;
                    float mean2 = tv[j]*inv;
                    float var = mean2 - mean*mean;
                    if (var < 0.f) var = 0.f;
                    int b = nn*1500 + tw*300 + f;
                    agg[b      ] = mean;
                    agg[b +  75] = (cnt > 0) ? mnv[j] : 0.f;
                    agg[b + 150] = (cnt > 0) ? mxv[j] : 0.f;
                    agg[b + 225] = sqrtf(var + 1e-5f);
                }
            }
        }
        if (tid == 0) {
            float deg = (cnt > 0) ? (float)cnt : 1.0f;
            float amp = logf(deg + 1.0f) * (1.0f/2.8332133440562162f);
            s_amp[nn] = amp; s_iamp[nn] = 1.0f/amp;
        }
    }
    __syncthreads();

    int nn = tid / 75;
    int o  = tid % 75;
    bool pact = tid < 300;

    // post: out[nn][o=tw*15+g] = qb[o] + r0 + amp*r1 + iamp*r2
    // weights in ORIGINAL layout qw[tw][f(900)][g(15)]: lanes (consecutive g,
    // 5 tower clusters per wave) -> coalesced 60B runs, sequential in f.
    if (pact) {
        int tw = o / FO, g = o % FO;
        float A = s_amp[nn], IA = s_iamp[nn];
        const float* W  = qw + tw*900*FO + g;
        const float* ag = &agg[nn*1500 + tw*300];
        float r0 = 0.f, r1 = 0.f, r2 = 0.f;
        for (int f = 0; f < 300; f++) {
            float av = ag[f];
            r0 += av * W[f*FO];
            r1 += av * W[(300+f)*FO];
            r2 += av * W[(600+f)*FO];
        }
        post[nn*76 + o] = qb[o] + r0 + A*r1 + IA*r2;
    }
    __syncthreads();
    // lin: out[nn][g2] = lb[g2] + sum_f post[nn][f] * lw[f*75+g2]  (coalesced in g2)
    if (pact) {
        const float* Wl = lw + o;
        const float* pv = &post[nn*76];
        float a = lb[o];
        for (int f = 0; f < 75; f++) a += pv[f] * Wl[f*75];
        g_hB[(n0+nn)*FI + o] = a;
    }
}

__global__ void k_bnstat() {
    int c = blockIdx.x;
    int t = threadIdx.x;
    double s = 0.0, s2 = 0.0;
    for (int n = t; n < N_NODES; n += 256) {
        float v = g_hB[n*FI + c];
        s += v; s2 += (double)v * v;
    }
    __shared__ double ps[256], ps2[256];
    ps[t] = s; ps2[t] = s2;
    __syncthreads();
    for (int off = 128; off > 0; off >>= 1) {
        if (t < off) { ps[t] += ps[t+off]; ps2[t] += ps2[t+off]; }
        __syncthreads();
    }
    if (t == 0) {
        double mu = ps[0] / N_NODES;
        double var = ps2[0] / N_NODES - mu*mu;
        if (var < 0.0) var = 0.0;
        g_mu[c]   = (float)mu;
        g_rsig[c] = (float)(1.0 / sqrt(var + 1e-5));
    }
}

__global__ void k_poolzero() {
    int i = blockIdx.x * blockDim.x + threadIdx.x;
    if (i < NG*FI) g_pool[i] = 0.f;
}

__global__ void k_pool(const int* __restrict__ batch, const float* __restrict__ gamma,
                       const float* __restrict__ beta) {
    int i = blockIdx.x * blockDim.x + threadIdx.x;
    if (i < N_NODES*FI) {
        int n = i / FI, c = i % FI;
        float v = (g_hB[i] - g_mu[c]) * g_rsig[c] * gamma[c] + beta[c];
        v = v > 0.f ? v : 0.f;
        atomicAdd(&g_pool[batch[n]*FI + c], v);
    }
}

__global__ void k_mlp(const float* __restrict__ w1, const float* __restrict__ b1,
                      const float* __restrict__ w2, const float* __restrict__ b2,
                      const float* __restrict__ w3, const float* __restrict__ b3,
                      float* __restrict__ out) {
    __shared__ float gin[FI], h1[50], h2[25];
    int gi = blockIdx.x;
    int t = threadIdx.x;
    if (t < FI) gin[t] = g_pool[gi*FI + t];
    __syncthreads();
    if (t < 50) {
        float s = b1[t];
        for (int f = 0; f < FI; f++) s += gin[f] * w1[f*50 + t];
        h1[t] = s > 0.f ? s : 0.f;
    }
    __syncthreads();
    if (t < 25) {
        float s = b2[t];
        for (int f = 0; f < 50; f++) s += h1[f] * w2[f*25 + t];
        h2[t] = s > 0.f ? s : 0.f;
    }
    __syncthreads();
    if (t == 0) {
        float s = b3[0];
        for (int f = 0; f < 25; f++) s += h2[f] * w3[f];
        out[gi] = s;
    }
}

extern "C" void kernel_launch(void* const* d_in, const int* in_sizes, int n_in,
                              void* d_out, int out_size, void* d_ws, size_t ws_size,
                              hipStream_t stream) {
    const int*   x          = (const int*)  d_in[0];
    const int*   edge_index = (const int*)  d_in[1];
    const int*   edge_attr  = (const int*)  d_in[2];
    const int*   batch      = (const int*)  d_in[3];
    const float* node_emb   = (const float*)d_in[4];
    const float* edge_emb   = (const float*)d_in[5];
    const float* edge_enc_w = (const float*)d_in[6];
    const float* edge_enc_b = (const float*)d_in[7];
    const float* pre_w      = (const float*)d_in[8];
    const float* pre_b      = (const float*)d_in[9];
    const float* post_w     = (const float*)d_in[10];
    const float* post_b     = (const float*)d_in[11];
    const float* lin_w      = (const float*)d_in[12];
    const float* lin_b      = (const float*)d_in[13];
    const float* bn_gamma   = (const float*)d_in[14];
    const float* bn_beta    = (const float*)d_in[15];
    const float* mlp_w1     = (const float*)d_in[16];
    const float* mlp_b1     = (const float*)d_in[17];
    const float* mlp_w2     = (const float*)d_in[18];
    const float* mlp_b2     = (const float*)d_in[19];
    const float* mlp_w3     = (const float*)d_in[20];
    const float* mlp_b3     = (const float*)d_in[21];
    float* out = (float*)d_out;

    const int* src = edge_index;
    const int* dst = edge_index + N_EDGES;

    k_embed<<<(N_NODES*FI + 255)/256, 256, 0, stream>>>(x, node_emb);
    k_zerodeg<<<(N_NODES + 255)/256, 256, 0, stream>>>();
    k_hist<<<(N_EDGES + 255)/256, 256, 0, stream>>>(dst);
    k_scan<<<1, 1024, 0, stream>>>();
    k_scatter<<<(N_EDGES + 255)/256, 256, 0, stream>>>(src, dst, edge_attr);
    k_ec<<<NL, 512, 0, stream>>>(edge_emb, edge_enc_w, edge_enc_b, pre_w, pre_b);

    for (int l = 0; l < NL; l++) {
        const float* pw  = pre_w  + l*TOW*(3*FI)*FI;
        const float* qw  = post_w + l*TOW*900*FO;
        const float* qb  = post_b + l*TOW*FO;
        const float* lw  = lin_w  + l*(TOW*FO)*(TOW*FO);
        const float* lb  = lin_b  + l*TOW*FO;
        const float* gamP = bn_gamma + (l > 0 ? (l-1)*FI : 0);
        const float* betP = bn_beta  + (l > 0 ? (l-1)*FI : 0);

        k_hw<<<N_NODES/NPB, 256, 0, stream>>>(pw, gamP, betP, l == 0 ? 1 : 0);
        k_fuse<<<N_NODES/NPN, 384, 0, stream>>>(l, qw, qb, lw, lb);
        k_bnstat<<<FI, 256, 0, stream>>>();
    }

    k_poolzero<<<(NG*FI + 255)/256, 256, 0, stream>>>();
    k_pool<<<(N_NODES*FI + 255)/256, 256, 0, stream>>>(batch, bn_gamma + 3*FI, bn_beta + 3*FI);
    k_mlp<<<NG, 128, 0, stream>>>(mlp_w1, mlp_b1, mlp_w2, mlp_b2, mlp_w3, mlp_b3, out);
}

// Round 6
// 1214.944 us; speedup vs baseline: 3.0391x; 2.3781x over previous
//
#include <hip/hip_runtime.h>
#include <math.h>

#define N_NODES 16384
#define N_EDGES 262144
#define TOW 5
#define FI 75            // F_IN
#define FO 15            // F_OUT
#define DE 50
#define NL 4
#define NG 256
#define HWP 752          // padded node stride: [hWi 0..374][pad][hWj 376..750][pad]
#define AGS 1504         // agg row stride (1500 + pad, 16B aligned)
#define PNN 8            // nodes per k_post block

static __device__ __attribute__((aligned(16))) float g_hA[N_NODES*FI];
static __device__ __attribute__((aligned(16))) float g_hB[N_NODES*FI];
static __device__ __attribute__((aligned(16))) float g_hW[N_NODES*HWP];
static __device__ __attribute__((aligned(16))) float g_ec[NL*4*376];
static __device__ int   g_deg[N_NODES];
static __device__ int   g_rowstart[N_NODES+1];
static __device__ int   g_cursor[N_NODES];
static __device__ int   g_edge[N_EDGES];
static __device__ float g_mu[FI];
static __device__ float g_rsig[FI];
static __device__ float g_pool[NG*FI];

__global__ void k_embed(const int* __restrict__ x, const float* __restrict__ node_emb) {
    int i = blockIdx.x * blockDim.x + threadIdx.x;
    if (i < N_NODES*FI) {
        int n = i / FI, f = i % FI;
        g_hA[i] = node_emb[x[n]*FI + f];
    }
}

__global__ void k_zerodeg() {
    int i = blockIdx.x * blockDim.x + threadIdx.x;
    if (i < N_NODES) g_deg[i] = 0;
}

__global__ void k_hist(const int* __restrict__ dst) {
    int e = blockIdx.x * blockDim.x + threadIdx.x;
    if (e < N_EDGES) atomicAdd(&g_deg[dst[e]], 1);
}

__global__ void k_scan() {
    __shared__ int part[1024];
    int t = threadIdx.x;
    int base = t * 16;
    int loc[16];
    int s = 0;
    #pragma unroll
    for (int i = 0; i < 16; i++) { loc[i] = s; s += g_deg[base + i]; }
    part[t] = s;
    __syncthreads();
    for (int off = 1; off < 1024; off <<= 1) {
        int v = 0;
        if (t >= off) v = part[t - off];
        __syncthreads();
        if (t >= off) part[t] += v;
        __syncthreads();
    }
    int excl = (t == 0) ? 0 : part[t - 1];
    #pragma unroll
    for (int i = 0; i < 16; i++) {
        g_rowstart[base + i] = excl + loc[i];
        g_cursor[base + i]   = excl + loc[i];
    }
    if (t == 1023) g_rowstart[N_NODES] = part[1023];
}

__global__ void k_scatter(const int* __restrict__ src, const int* __restrict__ dst,
                          const int* __restrict__ attr) {
    int e = blockIdx.x * blockDim.x + threadIdx.x;
    if (e < N_EDGES) {
        int d = dst[e];
        int pos = atomicAdd(&g_cursor[d], 1);
        g_edge[pos] = src[e] | (attr[e] << 16);
    }
}

// all-layer edge contribution tables: g_ec[l][a][376]
__global__ void k_ec(const float* __restrict__ edge_emb, const float* __restrict__ edge_enc_w,
                     const float* __restrict__ edge_enc_b, const float* __restrict__ pre_w,
                     const float* __restrict__ pre_b) {
    int l = blockIdx.x;
    const float* eew = edge_enc_w + l*DE*FI;
    const float* eeb = edge_enc_b + l*FI;
    const float* pw  = pre_w + l*TOW*3*FI*FI;
    const float* pb  = pre_b + l*TOW*FI;
    __shared__ float e_enc[4*FI];
    int t = threadIdx.x;
    if (t < 4*FI) {
        int a = t / FI, f = t % FI;
        float s = eeb[f];
        for (int d = 0; d < DE; d++) s += edge_emb[a*DE + d] * eew[d*FI + f];
        e_enc[t] = s;
    }
    __syncthreads();
    for (int o = t; o < 4*376; o += blockDim.x) {
        int a = o / 376;
        int r = o % 376;
        float s = 0.f;
        if (r < TOW*FI) {
            int tw = r / FI, g = r % FI;
            s = pb[tw*FI + g];
            const float* W = pw + (tw*(3*FI) + 2*FI)*FI + g;
            for (int f = 0; f < FI; f++) s += e_enc[a*FI + f] * W[f*FI];
        }
        g_ec[l*1504 + o] = s;
    }
}

// node transform (coalesced scalar weight loads, lane = output dim),
// fused BN+ReLU of previous layer's output
#define NPB 8
__global__ void k_hw(const float* __restrict__ pw, const float* __restrict__ gamma,
                     const float* __restrict__ beta, int first) {
    __shared__ float hsh[NPB*FI];
    int n0 = blockIdx.x * NPB;
    int tid = threadIdx.x;
    for (int i = tid; i < NPB*FI; i += blockDim.x) {
        int idx = (n0 + i/FI)*FI + (i % FI);
        float v;
        if (first) {
            v = g_hA[idx];
        } else {
            int c = i % FI;
            v = (g_hB[idx] - g_mu[c]) * g_rsig[c] * gamma[c] + beta[c];
            v = v > 0.f ? v : 0.f;
        }
        hsh[i] = v;
    }
    __syncthreads();
    for (int o = tid; o < 2*TOW*FI; o += blockDim.x) {
        int half = o / (TOW*FI);
        int r = o % (TOW*FI);
        int tw = r / FI, g = r % FI;
        const float* W = pw + (tw*(3*FI) + half*FI)*FI + g;
        float acc[NPB];
        #pragma unroll
        for (int nn = 0; nn < NPB; nn++) acc[nn] = 0.f;
        for (int f = 0; f < FI; f++) {
            float w = W[f*FI];
            #pragma unroll
            for (int nn = 0; nn < NPB; nn++) acc[nn] += hsh[nn*FI + f] * w;
        }
        #pragma unroll
        for (int nn = 0; nn < NPB; nn++)
            g_hW[(n0+nn)*HWP + half*376 + r] = acc[nn];
    }
}

// per-node edge aggregation, 1 node/block, 384 threads (4 el-lanes x 94 quads).
// Edge words staged in LDS; gather loop unrolled x4 -> 8 independent loads
// in flight per thread. Result written to ws agg[n][AGS] as one coalesced burst.
__global__ __launch_bounds__(384) void k_edge(int l, float* __restrict__ agg) {
    __shared__ int   es[64];
    __shared__ float aggl[AGS];
    int n = blockIdx.x;
    int tid = threadIdx.x;
    int el = tid & 3;
    int q  = tid >> 2;
    bool act = q < 94;
    const float* ec = g_ec + l*1504;
    int e0 = g_rowstart[n], e1 = g_rowstart[n+1];
    int cnt = e1 - e0;

    if (tid < 4) aggl[1500 + tid] = 0.f;

    float s0=0.f,s1=0.f,s2=0.f,s3=0.f;
    float t0=0.f,t1=0.f,t2=0.f,t3=0.f;
    float mn0=1e30f,mn1=1e30f,mn2=1e30f,mn3=1e30f;
    float mx0=-1e30f,mx1=-1e30f,mx2=-1e30f,mx3=-1e30f;
    float h0=0.f,h1=0.f,h2=0.f,h3=0.f;
    if (act) {
        float4 hv = *(const float4*)&g_hW[n*HWP + 4*q];
        h0=hv.x; h1=hv.y; h2=hv.z; h3=hv.w;
    }

    for (int base = e0; base < e1; base += 64) {
        int mcnt = min(64, e1 - base);
        __syncthreads();
        if (tid < mcnt) es[tid] = g_edge[base + tid];
        __syncthreads();
        int nit = (mcnt + 15) >> 4;
        for (int it = 0; it < nit; ++it) {
            int ib = it*16 + el;
            int i0 = ib, i1 = ib+4, i2 = ib+8, i3 = ib+12;
            int pk0 = es[i0 < mcnt ? i0 : 0];
            int pk1 = es[i1 < mcnt ? i1 : 0];
            int pk2 = es[i2 < mcnt ? i2 : 0];
            int pk3 = es[i3 < mcnt ? i3 : 0];
            if (act) {
                float4 hj0 = *(const float4*)&g_hW[(pk0 & 0xFFFF)*HWP + 376 + 4*q];
                float4 hj1 = *(const float4*)&g_hW[(pk1 & 0xFFFF)*HWP + 376 + 4*q];
                float4 hj2 = *(const float4*)&g_hW[(pk2 & 0xFFFF)*HWP + 376 + 4*q];
                float4 hj3 = *(const float4*)&g_hW[(pk3 & 0xFFFF)*HWP + 376 + 4*q];
                float4 ev0 = *(const float4*)&ec[(pk0 >> 16)*376 + 4*q];
                float4 ev1 = *(const float4*)&ec[(pk1 >> 16)*376 + 4*q];
                float4 ev2 = *(const float4*)&ec[(pk2 >> 16)*376 + 4*q];
                float4 ev3 = *(const float4*)&ec[(pk3 >> 16)*376 + 4*q];
                #define ACCUM(ii, hj, ev)                                        \
                    if (ii < mcnt) {                                             \
                        float m0 = h0 + hj.x + ev.x;                             \
                        float m1 = h1 + hj.y + ev.y;                             \
                        float m2 = h2 + hj.z + ev.z;                             \
                        float m3 = h3 + hj.w + ev.w;                             \
                        s0 += m0; s1 += m1; s2 += m2; s3 += m3;                  \
                        t0 += m0*m0; t1 += m1*m1; t2 += m2*m2; t3 += m3*m3;      \
                        mn0 = fminf(mn0,m0); mn1 = fminf(mn1,m1);                \
                        mn2 = fminf(mn2,m2); mn3 = fminf(mn3,m3);                \
                        mx0 = fmaxf(mx0,m0); mx1 = fmaxf(mx1,m1);                \
                        mx2 = fmaxf(mx2,m2); mx3 = fmaxf(mx3,m3);                \
                    }
                ACCUM(i0, hj0, ev0)
                ACCUM(i1, hj1, ev1)
                ACCUM(i2, hj2, ev2)
                ACCUM(i3, hj3, ev3)
                #undef ACCUM
            }
        }
    }
    #define RSUM(v) v += __shfl_xor(v,1); v += __shfl_xor(v,2);
    #define RMIN(v) v = fminf(v,__shfl_xor(v,1)); v = fminf(v,__shfl_xor(v,2));
    #define RMAX(v) v = fmaxf(v,__shfl_xor(v,1)); v = fmaxf(v,__shfl_xor(v,2));
    RSUM(s0) RSUM(s1) RSUM(s2) RSUM(s3)
    RSUM(t0) RSUM(t1) RSUM(t2) RSUM(t3)
    RMIN(mn0) RMIN(mn1) RMIN(mn2) RMIN(mn3)
    RMAX(mx0) RMAX(mx1) RMAX(mx2) RMAX(mx3)

    __syncthreads();
    if (act && el == 0) {
        float inv = 1.0f / ((cnt > 0) ? (float)cnt : 1.0f);
        float sv[4]  = {s0,s1,s2,s3};
        float tv[4]  = {t0,t1,t2,t3};
        float mnv[4] = {mn0,mn1,mn2,mn3};
        float mxv[4] = {mx0,mx1,mx2,mx3};
        #pragma unroll
        for (int j = 0; j < 4; j++) {
            int c = 4*q + j;
            if (c < TOW*FI) {
                int tw = c / FI, f = c - tw*FI;
                float mean  = sv[j]*inv;
                float mean2 = tv[j]*inv;
                float var = mean2 - mean*mean;
                if (var < 0.f) var = 0.f;
                int b = tw*300 + f;
                aggl[b      ] = mean;
                aggl[b +  75] = (cnt > 0) ? mnv[j] : 0.f;
                aggl[b + 150] = (cnt > 0) ? mxv[j] : 0.f;
                aggl[b + 225] = sqrtf(var + 1e-5f);
            }
        }
    }
    __syncthreads();
    if (tid < 376)
        *(float4*)&agg[(size_t)n*AGS + 4*tid] = *(const float4*)&aggl[4*tid];
}

// post GEMM + lin: 8 nodes/block, 384 threads, thread=(o,p) K-split 5x60,
// weights read once per block (amortized over 8 nodes), f unrolled x4.
__global__ __launch_bounds__(384) void
k_post(const float* __restrict__ agg, const float* __restrict__ qw,
       const float* __restrict__ qb, const float* __restrict__ lw,
       const float* __restrict__ lb) {
    __shared__ __align__(16) float aggs[PNN][AGS];   // 48.1 KB
    __shared__ float part[5*75*9];                   // 13.5 KB (pad 9: bank-safe)
    __shared__ float post[PNN][76];
    __shared__ float s_amp[PNN], s_iamp[PNN];
    int tid = threadIdx.x;
    int n0 = blockIdx.x * PNN;

    for (int i = tid; i < PNN*376; i += 384) {
        int nn = i / 376, t4 = i % 376;
        *(float4*)&aggs[nn][4*t4] = *(const float4*)&agg[(size_t)(n0+nn)*AGS + 4*t4];
    }
    if (tid < PNN) {
        int cnt = g_rowstart[n0+tid+1] - g_rowstart[n0+tid];
        float deg = (cnt > 0) ? (float)cnt : 1.0f;
        float amp = logf(deg + 1.0f) * (1.0f/2.8332133440562162f);
        s_amp[tid] = amp; s_iamp[tid] = 1.0f/amp;
    }
    __syncthreads();

    int o = tid % 75, p = tid / 75;
    if (tid < 375) {
        int tw = o / FO, g = o % FO;
        const float* W = qw + tw*900*FO + g;
        float a0[PNN], a1[PNN], a2[PNN];
        #pragma unroll
        for (int nn = 0; nn < PNN; nn++) { a0[nn]=0.f; a1[nn]=0.f; a2[nn]=0.f; }
        int f0 = p*60;
        for (int fq = 0; fq < 15; ++fq) {
            int f = f0 + fq*4;
            float w0a = W[(f  )*FO], w0b = W[(f+1)*FO], w0c = W[(f+2)*FO], w0d = W[(f+3)*FO];
            float w1a = W[(300+f)*FO], w1b = W[(301+f)*FO], w1c = W[(302+f)*FO], w1d = W[(303+f)*FO];
            float w2a = W[(600+f)*FO], w2b = W[(601+f)*FO], w2c = W[(602+f)*FO], w2d = W[(603+f)*FO];
            #pragma unroll
            for (int nn = 0; nn < PNN; nn++) {
                float4 av = *(const float4*)&aggs[nn][tw*300 + f];
                a0[nn] += av.x*w0a + av.y*w0b + av.z*w0c + av.w*w0d;
                a1[nn] += av.x*w1a + av.y*w1b + av.z*w1c + av.w*w1d;
                a2[nn] += av.x*w2a + av.y*w2b + av.z*w2c + av.w*w2d;
            }
        }
        #pragma unroll
        for (int nn = 0; nn < PNN; nn++)
            part[p*675 + o*9 + nn] = a0[nn] + s_amp[nn]*a1[nn] + s_iamp[nn]*a2[nn];
    }
    __syncthreads();
    if (tid < 75) {
        #pragma unroll
        for (int nn = 0; nn < PNN; nn++) {
            float s = qb[tid];
            #pragma unroll
            for (int p2 = 0; p2 < 5; p2++) s += part[p2*675 + tid*9 + nn];
            post[nn][tid] = s;
        }
    }
    __syncthreads();
    if (tid < 300) {
        int oo = tid % 75, nna = tid / 75;
        #pragma unroll
        for (int h = 0; h < 2; ++h) {
            int nn = nna + 4*h;
            const float* Wl = lw + oo;
            float s = lb[oo];
            for (int f = 0; f < 75; f++) s += post[nn][f] * Wl[f*75];
            g_hB[(n0+nn)*FI + oo] = s;
        }
    }
}

__global__ void k_bnstat() {
    int c = blockIdx.x;
    int t = threadIdx.x;
    double s = 0.0, s2 = 0.0;
    for (int n = t; n < N_NODES; n += 256) {
        float v = g_hB[n*FI + c];
        s += v; s2 += (double)v * v;
    }
    __shared__ double ps[256], ps2[256];
    ps[t] = s; ps2[t] = s2;
    __syncthreads();
    for (int off = 128; off > 0; off >>= 1) {
        if (t < off) { ps[t] += ps[t+off]; ps2[t] += ps2[t+off]; }
        __syncthreads();
    }
    if (t == 0) {
        double mu = ps[0] / N_NODES;
        double var = ps2[0] / N_NODES - mu*mu;
        if (var < 0.0) var = 0.0;
        g_mu[c]   = (float)mu;
        g_rsig[c] = (float)(1.0 / sqrt(var + 1e-5));
    }
}

__global__ void k_poolzero() {
    int i = blockIdx.x * blockDim.x + threadIdx.x;
    if (i < NG*FI) g_pool[i] = 0.f;
}

__global__ void k_pool(const int* __restrict__ batch, const float* __restrict__ gamma,
                       const float* __restrict__ beta) {
    int i = blockIdx.x * blockDim.x + threadIdx.x;
    if (i < N_NODES*FI) {
        int n = i / FI, c = i % FI;
        float v = (g_hB[i] - g_mu[c]) * g_rsig[c] * gamma[c] + beta[c];
        v = v > 0.f ? v : 0.f;
        atomicAdd(&g_pool[batch[n]*FI + c], v);
    }
}

__global__ void k_mlp(const float* __restrict__ w1, const float* __restrict__ b1,
                      const float* __restrict__ w2, const float* __restrict__ b2,
                      const float* __restrict__ w3, const float* __restrict__ b3,
                      float* __restrict__ out) {
    __shared__ float gin[FI], h1[50], h2[25];
    int gi = blockIdx.x;
    int t = threadIdx.x;
    if (t < FI) gin[t] = g_pool[gi*FI + t];
    __syncthreads();
    if (t < 50) {
        float s = b1[t];
        for (int f = 0; f < FI; f++) s += gin[f] * w1[f*50 + t];
        h1[t] = s > 0.f ? s : 0.f;
    }
    __syncthreads();
    if (t < 25) {
        float s = b2[t];
        for (int f = 0; f < 50; f++) s += h1[f] * w2[f*25 + t];
        h2[t] = s > 0.f ? s : 0.f;
    }
    __syncthreads();
    if (t == 0) {
        float s = b3[0];
        for (int f = 0; f < 25; f++) s += h2[f] * w3[f];
        out[gi] = s;
    }
}

extern "C" void kernel_launch(void* const* d_in, const int* in_sizes, int n_in,
                              void* d_out, int out_size, void* d_ws, size_t ws_size,
                              hipStream_t stream) {
    const int*   x          = (const int*)  d_in[0];
    const int*   edge_index = (const int*)  d_in[1];
    const int*   edge_attr  = (const int*)  d_in[2];
    const int*   batch      = (const int*)  d_in[3];
    const float* node_emb   = (const float*)d_in[4];
    const float* edge_emb   = (const float*)d_in[5];
    const float* edge_enc_w = (const float*)d_in[6];
    const float* edge_enc_b = (const float*)d_in[7];
    const float* pre_w      = (const float*)d_in[8];
    const float* pre_b      = (const float*)d_in[9];
    const float* post_w     = (const float*)d_in[10];
    const float* post_b     = (const float*)d_in[11];
    const float* lin_w      = (const float*)d_in[12];
    const float* lin_b      = (const float*)d_in[13];
    const float* bn_gamma   = (const float*)d_in[14];
    const float* bn_beta    = (const float*)d_in[15];
    const float* mlp_w1     = (const float*)d_in[16];
    const float* mlp_b1     = (const float*)d_in[17];
    const float* mlp_w2     = (const float*)d_in[18];
    const float* mlp_b2     = (const float*)d_in[19];
    const float* mlp_w3     = (const float*)d_in[20];
    const float* mlp_b3     = (const float*)d_in[21];
    float* out = (float*)d_out;
    float* agg = (float*)d_ws;      // N_NODES*AGS floats = 98.6 MB

    const int* src = edge_index;
    const int* dst = edge_index + N_EDGES;

    k_embed<<<(N_NODES*FI + 255)/256, 256, 0, stream>>>(x, node_emb);
    k_zerodeg<<<(N_NODES + 255)/256, 256, 0, stream>>>();
    k_hist<<<(N_EDGES + 255)/256, 256, 0, stream>>>(dst);
    k_scan<<<1, 1024, 0, stream>>>();
    k_scatter<<<(N_EDGES + 255)/256, 256, 0, stream>>>(src, dst, edge_attr);
    k_ec<<<NL, 512, 0, stream>>>(edge_emb, edge_enc_w, edge_enc_b, pre_w, pre_b);

    for (int l = 0; l < NL; l++) {
        const float* pw  = pre_w  + l*TOW*(3*FI)*FI;
        const float* qw  = post_w + l*TOW*900*FO;
        const float* qb  = post_b + l*TOW*FO;
        const float* lw  = lin_w  + l*(TOW*FO)*(TOW*FO);
        const float* lb  = lin_b  + l*TOW*FO;
        const float* gamP = bn_gamma + (l > 0 ? (l-1)*FI : 0);
        const float* betP = bn_beta  + (l > 0 ? (l-1)*FI : 0);

        k_hw<<<N_NODES/NPB, 256, 0, stream>>>(pw, gamP, betP, l == 0 ? 1 : 0);
        k_edge<<<N_NODES, 384, 0, stream>>>(l, agg);
        k_post<<<N_NODES/PNN, 384, 0, stream>>>(agg, qw, qb, lw, lb);
        k_bnstat<<<FI, 256, 0, stream>>>();
    }

    k_poolzero<<<(NG*FI + 255)/256, 256, 0, stream>>>();
    k_pool<<<(N_NODES*FI + 255)/256, 256, 0, stream>>>(batch, bn_gamma + 3*FI, bn_beta + 3*FI);
    k_mlp<<<NG, 128, 0, stream>>>(mlp_w1, mlp_b1, mlp_w2, mlp_b2, mlp_w3, mlp_b3, out);
}